// Round 6
// baseline (639.075 us; speedup 1.0000x reference)
//
#include <hip/hip_runtime.h>
#include <math.h>

// DIN-style sequence attention, R6.
// R5 -> R6: single-variable experiment. Measured occupancy has tracked the
// __launch_bounds__ min-waves arg EXACTLY for four rounds (2->23%, 4->44%,
// 3->31%x2) even when VGPR(84)/LDS(25KB) allow 6 blocks/CU -- the hint is
// empirically acting as a residency cap. This round: (256,6). VGPR cap
// 512/6=85 >= current 84, LDS 25088 <= 160K/6. Everything else unchanged.

constexpr int BATCH = 4096;
constexpr int T  = 200;
constexpr int H  = 64;     // D_IN = 4H = 256
constexpr int D1 = 80;
constexpr int D2 = 40;
constexpr int MROW = 208;  // 13 M-tiles of 16
constexpr int KS2 = 104;   // sH1 row stride (96+8 pad)

// ws layout (bytes)
constexpr size_t WS_B1  = 0;          // 20 frags * 64 lanes * 16B = 20480
constexpr size_t WS_B2  = 20480;      // 9 frags * 64 lanes * 16B = 9216
constexpr size_t WS_B2V = 29696;      // 48 floats
constexpr size_t WS_WDV = 29888;      // 48 floats
constexpr size_t WS_QP  = 32768;      // 4096*80 floats
constexpr size_t WS_TOTAL = WS_QP + (size_t)BATCH * D1 * 4;

typedef __attribute__((ext_vector_type(8))) __bf16 bf16x8;
typedef __attribute__((ext_vector_type(4))) float  floatx4;

__device__ __forceinline__ float fsig(float x) {
    return __builtin_amdgcn_rcpf(1.0f + __expf(-x));
}
#define MFMA16(a, b, c) __builtin_amdgcn_mfma_f32_16x16x32_bf16((a), (b), (c), 0, 0, 0)

// ---- prep 1: fragment-ordered bf16 weights (batch-independent) ----
// B1 covers K=128: k<64 -> W1b-W1c ; k>=64 -> W1d row (k-64).
// frag f = n*4+ks; lane (col=lane&15, quad=lane>>4) holds
// B[k=ks*32+quad*8+e][n*16+col].
__global__ void prep_weights(const float* __restrict__ W1,
                             const float* __restrict__ W2g,
                             const float* __restrict__ b2g,
                             const float* __restrict__ Wdg,
                             __bf16* __restrict__ wsB1, __bf16* __restrict__ wsB2,
                             float* __restrict__ wsB2v, float* __restrict__ wsWdv)
{
    const int gid = blockIdx.x * 256 + threadIdx.x;
    const int gstride = gridDim.x * 256;
    for (int u = gid; u < 20 * 64; u += gstride) {
        const int f = u >> 6, lane = u & 63;
        const int n = f >> 2, ks = f & 3;
        const int col = lane & 15, quad = lane >> 4;
        const int j = n * 16 + col;
        __bf16 frag[8];
        #pragma unroll
        for (int e = 0; e < 8; ++e) {
            const int kk = ks * 32 + quad * 8 + e;
            const float v = (kk < 64)
                ? (W1[(64 + kk) * D1 + j] - W1[(128 + kk) * D1 + j])
                : W1[(128 + kk) * D1 + j];          // (192+(kk-64)) == 128+kk
            frag[e] = (__bf16)v;
        }
        *(bf16x8*)&wsB1[u * 8] = *(bf16x8*)frag;
    }
    for (int u = gid; u < 9 * 64; u += gstride) {
        const int f = u >> 6, lane = u & 63;
        const int n3 = f / 3, ks3 = f % 3;
        const int col = lane & 15, quad = lane >> 4;
        const int j = n3 * 16 + col;
        __bf16 frag[8];
        #pragma unroll
        for (int e = 0; e < 8; ++e) {
            const int kk = ks3 * 32 + quad * 8 + e;
            frag[e] = (j < D2 && kk < D1) ? (__bf16)W2g[kk * D2 + j] : (__bf16)0.f;
        }
        *(bf16x8*)&wsB2[u * 8] = *(bf16x8*)frag;
    }
    if (gid < 48) {
        wsB2v[gid] = (gid < D2) ? b2g[gid] : 0.f;
        wsWdv[gid] = (gid < D2) ? Wdg[gid] : 0.f;
    }
}

// ---- prep 2: qpart[b][j] = b1[j] + q_b . (W1a + W1c), all b ----
__global__ __launch_bounds__(256) void prep_qpart(
    const float* __restrict__ q_g, const float* __restrict__ W1,
    const float* __restrict__ b1g, float* __restrict__ wsQp)
{
    __shared__ float sW1s[H * D1];   // 20 KB
    __shared__ float sq[16 * H];     // 4 KB
    const int tid = threadIdx.x;
    const int b0 = blockIdx.x * 16;
    for (int idx = tid; idx < H * D1; idx += 256) {
        const int i = idx / D1, j = idx % D1;
        sW1s[idx] = W1[i * D1 + j] + W1[(128 + i) * D1 + j];
    }
    for (int idx = tid; idx < 16 * H; idx += 256)
        sq[idx] = q_g[(size_t)b0 * H + idx];
    __syncthreads();
    for (int idx = tid; idx < 16 * D1; idx += 256) {
        const int bl = idx / D1, j = idx % D1;
        float acc = b1g[j];
        #pragma unroll 8
        for (int i = 0; i < H; ++i)
            acc += sq[bl * H + i] * sW1s[i * D1 + j];
        wsQp[(size_t)(b0 + bl) * D1 + j] = acc;
    }
}

// ---- main ----
template<bool QWS>
__global__ __launch_bounds__(256, 6) void din_main6(
    const float* __restrict__ q_g, const float* __restrict__ keys_g,
    const int* __restrict__ len_g, const float* __restrict__ W1,
    const float* __restrict__ b1g,
    const __bf16* __restrict__ wsB1, const __bf16* __restrict__ wsB2,
    const float* __restrict__ wsB2v, const float* __restrict__ wsWdv,
    const float* __restrict__ wsQp, float* __restrict__ out)
{
    __shared__ __align__(16) __bf16 sB2f[9 * 64 * 8];     // 9.2 KB frag-ordered
    __shared__ __align__(16) __bf16 sH1[4][16][KS2];      // 13.3 KB per-wave H1
    __shared__ __align__(16) float sS[MROW];
    __shared__ __align__(16) float sQp[D1];
    __shared__ __align__(16) float sQ[H];                 // fallback only
    __shared__ __align__(16) float sRed[8];
    __shared__ __align__(16) float sPart[4][H];

    const int b    = blockIdx.x;
    const int tid  = threadIdx.x;
    const int lane = tid & 63;
    const int wave = tid >> 6;
    const int quad = lane >> 4;
    const int col  = lane & 15;
    const int len  = len_g[b];
    const float* __restrict__ qrow  = q_g + (size_t)b * H;
    const float* __restrict__ kbase = keys_g + (size_t)b * T * H;

    // ---- stage B2 frags -> LDS (coalesced float4 copy) ----
    {
        const float4* src = (const float4*)wsB2;
        float4* dst = (float4*)sB2f;
        for (int idx = tid; idx < 9 * 64; idx += 256) dst[idx] = src[idx];
    }
    if (QWS) { if (tid < D1) sQp[tid] = wsQp[(size_t)b * D1 + tid]; }
    else     { if (tid < H)  sQ[tid]  = qrow[tid]; }

    // per-lane q values for the q*k fragments (quad-broadcast loads)
    const float4 qa0 = *(const float4*)(qrow + quad * 8);
    const float4 qa1 = *(const float4*)(qrow + quad * 8 + 4);
    const float4 qb0 = *(const float4*)(qrow + 32 + quad * 8);
    const float4 qb1 = *(const float4*)(qrow + 32 + quad * 8 + 4);
    float qv[16] = {qa0.x, qa0.y, qa0.z, qa0.w, qa1.x, qa1.y, qa1.z, qa1.w,
                    qb0.x, qb0.y, qb0.z, qb0.w, qb1.x, qb1.y, qb1.z, qb1.w};

    // per-lane layer-2 epilogue constants + qpart values
    float b2v[3], wdv[3], qpv[5];
    #pragma unroll
    for (int n = 0; n < 3; ++n) {
        b2v[n] = wsB2v[n * 16 + col];
        wdv[n] = wsWdv[n * 16 + col];
    }

    // B1 fragments (compiler re-loads as needed; L1-hot, 20KB broadcast)
    bf16x8 B1f[20];
    #pragma unroll
    for (int f = 0; f < 20; ++f) B1f[f] = *(const bf16x8*)&wsB1[(f * 64 + lane) * 8];

    // zero own wave's sH1 pad cols 80..95 (wave-local, no barrier needed)
    {
        ushort4 z = {0, 0, 0, 0};
        *(ushort4*)&sH1[wave][lane >> 2][80 + (lane & 3) * 4] = z;
    }
    __syncthreads();   // sB2f + sQp (+ sQ) visible

    if (!QWS) {        // inline qpart fallback (ws too small)
        if (tid < D1) {
            float qp = b1g[tid];
            #pragma unroll 8
            for (int i = 0; i < H; ++i)
                qp += sQ[i] * (W1[i * D1 + tid] + W1[(128 + i) * D1 + tid]);
            sQp[tid] = qp;
        }
        __syncthreads();
    }
    #pragma unroll
    for (int n = 0; n < 5; ++n) qpv[n] = sQp[n * 16 + col];

    // ---- Phase B: MFMA scorer; waves stream, no barriers ----
    for (int mt = wave; mt < 13; mt += 4) {
        const int Mb = mt * 16;
        const int rowc = min(Mb + col, T - 1);       // clamp: tile 12 tail rows
        const float* kp = kbase + (size_t)rowc * H + quad * 8;
        const float4 v0 = *(const float4*)(kp);
        const float4 v1 = *(const float4*)(kp + 4);
        const float4 v2 = *(const float4*)(kp + 32);
        const float4 v3 = *(const float4*)(kp + 36);
        const float kf[16] = {v0.x, v0.y, v0.z, v0.w, v1.x, v1.y, v1.z, v1.w,
                              v2.x, v2.y, v2.z, v2.w, v3.x, v3.y, v3.z, v3.w};
        bf16x8 A0, A1, A2, A3;
        #pragma unroll
        for (int e = 0; e < 8; ++e) {
            A0[e] = (__bf16)kf[e];
            A1[e] = (__bf16)kf[8 + e];
            A2[e] = (__bf16)(qv[e] * kf[e]);          // q*k, k segment 0..31
            A3[e] = (__bf16)(qv[8 + e] * kf[8 + e]);  // q*k, k segment 32..63
        }
        // layer 1: S1 = [k, q*k][16x128] @ W1eff[128x80]
        #pragma unroll
        for (int n = 0; n < 5; ++n) {
            floatx4 acc = {0.f, 0.f, 0.f, 0.f};
            acc = MFMA16(A0, B1f[n * 4 + 0], acc);
            acc = MFMA16(A1, B1f[n * 4 + 1], acc);
            acc = MFMA16(A2, B1f[n * 4 + 2], acc);
            acc = MFMA16(A3, B1f[n * 4 + 3], acc);
            const float qpn = qpv[n];
            #pragma unroll
            for (int r = 0; r < 4; ++r)               // C/D: row=quad*4+r, col
                sH1[wave][quad * 4 + r][n * 16 + col] = (__bf16)fsig(acc[r] + qpn);
        }
        // layer 2: S2 = H1[16x80] @ W2[80x40]; A from own wave's LDS tile
        const bf16x8 C0 = *(const bf16x8*)&sH1[wave][col][quad * 8];
        const bf16x8 C1 = *(const bf16x8*)&sH1[wave][col][32 + quad * 8];
        const bf16x8 C2 = *(const bf16x8*)&sH1[wave][col][64 + quad * 8];
        float sp0 = 0.f, sp1 = 0.f, sp2 = 0.f, sp3 = 0.f;
        #pragma unroll
        for (int n = 0; n < 3; ++n) {
            floatx4 acc = {0.f, 0.f, 0.f, 0.f};
            #pragma unroll
            for (int ks = 0; ks < 3; ++ks) {          // B2 frags from LDS
                const bf16x8 Bf = *(const bf16x8*)&sB2f[((n * 3 + ks) * 64 + lane) * 8];
                acc = MFMA16(ks == 0 ? C0 : (ks == 1 ? C1 : C2), Bf, acc);
            }
            sp0 += fsig(acc[0] + b2v[n]) * wdv[n];
            sp1 += fsig(acc[1] + b2v[n]) * wdv[n];
            sp2 += fsig(acc[2] + b2v[n]) * wdv[n];
            sp3 += fsig(acc[3] + b2v[n]) * wdv[n];
        }
        #pragma unroll
        for (int off = 1; off <= 8; off <<= 1) {      // reduce 16 cols in quad-group
            sp0 += __shfl_xor(sp0, off, 64);
            sp1 += __shfl_xor(sp1, off, 64);
            sp2 += __shfl_xor(sp2, off, 64);
            sp3 += __shfl_xor(sp3, off, 64);
        }
        if (col == 0) {
            sS[Mb + quad * 4 + 0] = sp0;
            sS[Mb + quad * 4 + 1] = sp1;
            sS[Mb + quad * 4 + 2] = sp2;
            sS[Mb + quad * 4 + 3] = sp3;
        }
    }
    __syncthreads();

    // ---- Phase C: block softmax over T (mask t>=len, scale 1/8) ----
    const int t = tid;
    float score = -INFINITY;
    if (t < T && t < len) score = sS[t] * 0.125f;
    float m = score;
    #pragma unroll
    for (int off = 32; off >= 1; off >>= 1)
        m = fmaxf(m, __shfl_xor(m, off, 64));
    if (lane == 0) sRed[wave] = m;
    __syncthreads();
    m = fmaxf(fmaxf(sRed[0], sRed[1]), fmaxf(sRed[2], sRed[3]));

    float e = 0.0f;
    if (t < T && t < len) e = __expf(score - m);
    float l = e;
    #pragma unroll
    for (int off = 32; off >= 1; off >>= 1)
        l += __shfl_xor(l, off, 64);
    if (lane == 0) sRed[4 + wave] = l;
    if (t < T) sS[t] = e;     // own slot: raw score already consumed here
    __syncthreads();
    l = sRed[4] + sRed[5] + sRed[6] + sRed[7];
    const float inv_l = __builtin_amdgcn_rcpf(l);

    // ---- Phase D: out[b][h] = sum_t w_t * K[t][h] (global fp32, L2-hot) ----
    const int h = tid & 63;
    const int c = tid >> 6;                            // 4 chunks of 50
    float p = 0.0f;
    for (int t2 = c * 50; t2 < c * 50 + 50; ++t2)
        p += sS[t2] * kbase[(size_t)t2 * H + h];       // coalesced 256B rows
    sPart[c][h] = p;
    __syncthreads();
    if (tid < H)
        out[b * H + tid] = (sPart[0][tid] + sPart[1][tid] + sPart[2][tid] + sPart[3][tid]) * inv_l;
}

extern "C" void kernel_launch(void* const* d_in, const int* in_sizes, int n_in,
                              void* d_out, int out_size, void* d_ws, size_t ws_size,
                              hipStream_t stream) {
    const float* q    = (const float*)d_in[0];
    const float* keys = (const float*)d_in[1];
    const int*   lens = (const int*)d_in[2];
    const float* W1   = (const float*)d_in[3];
    const float* b1   = (const float*)d_in[4];
    const float* W2   = (const float*)d_in[5];
    const float* b2   = (const float*)d_in[6];
    const float* Wd   = (const float*)d_in[7];
    const float* bd   = (const float*)d_in[8];
    float* outp = (float*)d_out;

    char* ws = (char*)d_ws;
    __bf16* wsB1 = (__bf16*)(ws + WS_B1);
    __bf16* wsB2 = (__bf16*)(ws + WS_B2);
    float* wsB2v = (float*)(ws + WS_B2V);
    float* wsWdv = (float*)(ws + WS_WDV);
    float* wsQp  = (float*)(ws + WS_QP);

    prep_weights<<<8, 256, 0, stream>>>(W1, W2, b2, Wd, wsB1, wsB2, wsB2v, wsWdv);
    const bool qws = ws_size >= WS_TOTAL;
    if (qws) {
        prep_qpart<<<BATCH / 16, 256, 0, stream>>>(q, W1, b1, wsQp);
        din_main6<true><<<BATCH, 256, 0, stream>>>(q, keys, lens, W1, b1,
                                                   wsB1, wsB2, wsB2v, wsWdv, wsQp, outp);
    } else {
        din_main6<false><<<BATCH, 256, 0, stream>>>(q, keys, lens, W1, b1,
                                                    wsB1, wsB2, wsB2v, wsWdv, wsQp, outp);
    }
}